// Round 9
// baseline (499.814 us; speedup 1.0000x reference)
//
#include <hip/hip_runtime.h>

typedef __bf16  bf16x4 __attribute__((ext_vector_type(4)));
typedef __bf16  bf16x8 __attribute__((ext_vector_type(8)));
typedef float   f32x4  __attribute__((ext_vector_type(4)));
typedef unsigned int u32;

constexpr int BM = 128, BN = 128, BK = 32;

// async global->LDS, 16B per lane. LDS dest is wave-uniform base + lane*16.
__device__ __forceinline__ void async_cp16(const __bf16* g, __bf16* lds) {
    __builtin_amdgcn_global_load_lds(
        (const __attribute__((address_space(1))) u32*)g,
        (__attribute__((address_space(3))) u32*)lds, 16, 0, 0);
}

// swizzled LDS offset (in shorts) of (row, 16B-slot q) for BK=32 tiles
__device__ __forceinline__ int swz(int row, int q) {
    return row * BK + (((q + (row >> 1)) & 3) << 3);
}

// ---------------------------------------------------------------------------
// NT GEMM (128x128xBK32): C[m,n] = sum_k A[m,k] * Bt[n,k]
// MFMA operands SWAPPED (mfma(bg,af)): D[m=B's n][n=A's m], so each lane's 4
// regs are 4 contiguous C-columns of one C-row -> bf16x4 stores (16 vs 64).
// EPI: 1 = bf16 store, 2 = +bias,leakyRelu -> bf16,
//      3 = bf16 partial at C0 + chunk*pstrideB,
//      4 = bf16 split across C0/C1/C2 by col/256
// ---------------------------------------------------------------------------
template<int EPI>
__launch_bounds__(256)
__global__ void gemm_nt(const __bf16* __restrict__ Aall, const __bf16* __restrict__ Ball,
                        const float* __restrict__ bias,
                        void* __restrict__ C0, void* __restrict__ C1, void* __restrict__ C2,
                        int N, int K, long ldb, long sA, long sB, long sC,
                        int nTx, int klen, long pstrideB)
{
    const int bx = blockIdx.x;
    const int chunk = bx / nTx;
    const int n0 = (bx - chunk * nTx) * BN;
    const int m0 = blockIdx.y * BM;
    const int bz = blockIdx.z;
    const int kbase = chunk * klen;

    const __bf16* A  = Aall + (long)bz * sA;
    const __bf16* Bt = Ball + (long)bz * sB;

    __shared__ alignas(16) __bf16 As[BM * BK];
    __shared__ alignas(16) __bf16 Bs[BN * BK];

    const int tid = threadIdx.x;
    const int wave = tid >> 6, lane = tid & 63;
    const int wm = (wave >> 1) * 64, wn = (wave & 1) * 64;
    const int quad = lane >> 4, l16 = lane & 15;

    const int row0 = tid >> 2, sl0 = tid & 3;
    const int ks0 = (sl0 - (row0 >> 1)) & 3;
    const int row1 = row0 + 64;
    const int ks1 = (sl0 - (row1 >> 1)) & 3;
    const __bf16* gA0 = A  + (long)(m0 + row0) * K + kbase + ks0 * 8;
    const __bf16* gA1 = A  + (long)(m0 + row1) * K + kbase + ks1 * 8;
    const __bf16* gB0 = Bt + (long)(n0 + row0) * ldb + kbase + ks0 * 8;
    const __bf16* gB1 = Bt + (long)(n0 + row1) * ldb + kbase + ks1 * 8;
    __bf16* ldsA0 = As + wave * 512;
    __bf16* ldsA1 = As + 2048 + wave * 512;
    __bf16* ldsB0 = Bs + wave * 512;
    __bf16* ldsB1 = Bs + 2048 + wave * 512;

    f32x4 acc[4][4];
    #pragma unroll
    for (int i = 0; i < 4; i++)
        #pragma unroll
        for (int j = 0; j < 4; j++) { f32x4 z = {0.f, 0.f, 0.f, 0.f}; acc[i][j] = z; }

    for (int kk = 0; kk < klen; kk += BK) {
        __syncthreads();
        async_cp16(gA0, ldsA0);
        async_cp16(gA1, ldsA1);
        async_cp16(gB0, ldsB0);
        async_cp16(gB1, ldsB1);
        gA0 += BK; gA1 += BK; gB0 += BK; gB1 += BK;
        __syncthreads();

        bf16x8 af[4], bg[4];
        #pragma unroll
        for (int i = 0; i < 4; i++) {
            af[i] = *(const bf16x8*)(As + swz(wm + i * 16 + l16, quad));
            bg[i] = *(const bf16x8*)(Bs + swz(wn + i * 16 + l16, quad));
        }
        #pragma unroll
        for (int i = 0; i < 4; i++)
            #pragma unroll
            for (int j = 0; j < 4; j++)
                acc[i][j] = __builtin_amdgcn_mfma_f32_16x16x32_bf16(bg[j], af[i], acc[i][j], 0, 0, 0);
    }

    char* cb = (char*)C0 + (EPI == 3 ? (long)chunk * pstrideB : 0);
    #pragma unroll
    for (int i = 0; i < 4; i++) {
        const int row = m0 + wm + i * 16 + l16;          // A's m -> D col (n) = l16
        #pragma unroll
        for (int j = 0; j < 4; j++) {
            const int colb = n0 + wn + j * 16 + quad * 4; // B's n -> D row = quad*4+r
            float4 bv4;
            if (EPI == 2) bv4 = *(const float4*)(bias + colb);
            bf16x4 pk;
            #pragma unroll
            for (int r = 0; r < 4; r++) {
                float c = acc[i][j][r];
                if (EPI == 2) { c += ((const float*)&bv4)[r]; c = c > 0.f ? c : 0.2f * c; }
                pk[r] = (__bf16)c;
            }
            if (EPI == 1 || EPI == 3)
                *(bf16x4*)((__bf16*)cb + (long)bz * sC + (long)row * N + colb) = pk;
            else if (EPI == 2)
                *(bf16x4*)((__bf16*)cb + (long)row * N + colb) = pk;
            else {  // EPI == 4: split by column segment of 256 (4-run never crosses)
                const int seg = colb >> 8;
                __bf16* dst = seg == 0 ? (__bf16*)C0 : (seg == 1 ? (__bf16*)C1 : (__bf16*)C2);
                *(bf16x4*)(dst + (long)row * 256 + (colb & 255)) = pk;
            }
        }
    }
}

// ---------------------------------------------------------------------------
// exp-scores, 64q x 64key tiles, operand-swapped MFMA: lane holds one query
// (l16) x 16 keys -> bf16x4 stores + per-lane row sum (2 shuffles).
// SC[q][key] = exp(scale*QK^T) (causal: exact 0 above diag); per-64-key-slot
// sums -> side[b][kt][q].
// ---------------------------------------------------------------------------
template<bool CAUSAL>
__launch_bounds__(256)
__global__ void scores_nt(const __bf16* __restrict__ Qall, const __bf16* __restrict__ Kall,
                          __bf16* __restrict__ SCall, float* __restrict__ side, float scale)
{
    constexpr int S = 4096, KD = 256;
    const int kt = blockIdx.x, mt = blockIdx.y;
    if (CAUSAL && kt > (mt | 1)) return;
    const int n0 = kt * 64, m0 = mt * 64;
    const int bz = blockIdx.z;
    const __bf16* Q  = Qall + (long)bz * S * KD;
    const __bf16* Kp = Kall + (long)bz * S * KD;

    __shared__ alignas(16) __bf16 As[64 * 64];
    __shared__ alignas(16) __bf16 Bs[64 * 64];

    const int tid = threadIdx.x;
    const int wave = tid >> 6, lane = tid & 63;
    const int quad = lane >> 4, l16 = lane & 15;
    const int wq = wave * 16;

    const int rowb = tid >> 3;                 // 0..31
    const int gslot = (tid & 7) ^ (rowb & 7);
    const __bf16* gA0 = Q  + (long)(m0 + rowb) * KD + gslot * 8;
    const __bf16* gA1 = Q  + (long)(m0 + 32 + rowb) * KD + gslot * 8;
    const __bf16* gB0 = Kp + (long)(n0 + rowb) * KD + gslot * 8;
    const __bf16* gB1 = Kp + (long)(n0 + 32 + rowb) * KD + gslot * 8;
    const int wb = (tid & ~63) * 8;

    f32x4 acc[4];
    #pragma unroll
    for (int j = 0; j < 4; j++) { f32x4 z = {0.f, 0.f, 0.f, 0.f}; acc[j] = z; }

    for (int kk = 0; kk < KD; kk += 64) {
        __syncthreads();
        async_cp16(gA0 + kk, As + wb);
        async_cp16(gA1 + kk, As + 2048 + wb);
        async_cp16(gB0 + kk, Bs + wb);
        async_cp16(gB1 + kk, Bs + 2048 + wb);
        __syncthreads();
        #pragma unroll
        for (int t2 = 0; t2 < 2; t2++) {
            const int ra = wq + l16;
            bf16x8 af = *(const bf16x8*)(As + ra * 64 + (((t2 * 4 + quad) ^ (ra & 7)) << 3));
            #pragma unroll
            for (int j = 0; j < 4; j++) {
                const int rb = j * 16 + l16;
                bf16x8 bg = *(const bf16x8*)(Bs + rb * 64 + (((t2 * 4 + quad) ^ (rb & 7)) << 3));
                acc[j] = __builtin_amdgcn_mfma_f32_16x16x32_bf16(bg, af, acc[j], 0, 0, 0);
            }
        }
    }

    // D[m=key_local][n=q_local]: lane (quad,l16) holds keys j*16+quad*4+r, query wq+l16
    __bf16* sc = SCall + (long)bz * S * S;
    const int q = m0 + wq + l16;
    float se = 0.f;
    #pragma unroll
    for (int j = 0; j < 4; j++) {
        const int kb = n0 + j * 16 + quad * 4;
        bf16x4 pk;
        #pragma unroll
        for (int r = 0; r < 4; r++) {
            float e = __expf(acc[j][r] * scale);
            if (CAUSAL && kt >= mt && kb + r > q) e = 0.f;   // exact 0 above diagonal
            pk[r] = (__bf16)e;
            se += e;
        }
        *(bf16x4*)(sc + (long)q * S + kb) = pk;
    }
    se += __shfl_xor(se, 16);
    se += __shfl_xor(se, 32);
    if (lane < 16)
        side[((long)bz * 64 + kt) * 4096 + q] = se;
}

// ---------------------------------------------------------------------------
// PV: pbuf_chunk[q][e] = sum_k SC[q,k] * Vt[e,k]. 128q x 64e x BK32, swapped
// MFMA -> lane holds one q x 4 contiguous e per (i,j) -> bf16x4 stores (8 vs 32).
// ---------------------------------------------------------------------------
template<int CMODE>
__launch_bounds__(256)
__global__ void pv_nt(const __bf16* __restrict__ SCall, const __bf16* __restrict__ Vt,
                      __bf16* __restrict__ pbuf, int nsplit, long pstrideE)
{
    constexpr int S = 4096, D = 256, R = 16384;
    const int bx = blockIdx.x;
    const int lin = (bx >> 5) * 8 + (bx & 7);
    const int nt = (bx >> 3) & 3;
    const int per_b = 32 * nsplit;
    const int bz = lin / per_b;
    const int rem = lin - bz * per_b;
    const int chunk = rem >> 5;
    const int m0 = (rem & 31) * 128;
    const int n0 = nt * 64;
    int kbase, klocal;
    if (CMODE == 2) { const int kl = (m0 + 128) / nsplit; kbase = chunk * kl; klocal = kl; }
    else            { const int kl = S / nsplit;          kbase = chunk * kl; klocal = kl; }

    const __bf16* A = SCall + (long)bz * S * S;
    const __bf16* B = Vt + (long)bz * S;          // row = e (stride R), col = key

    __shared__ alignas(16) __bf16 As[128 * 32];
    __shared__ alignas(16) __bf16 Bs[64 * 32];

    const int tid = threadIdx.x;
    const int wave = tid >> 6, lane = tid & 63;
    const int wm = (wave >> 1) * 64, wn2 = (wave & 1) * 32;
    const int quad = lane >> 4, l16 = lane & 15;

    const int row0 = tid >> 2, sl0 = tid & 3;
    const int ks0 = (sl0 - (row0 >> 1)) & 3;
    const int row1 = row0 + 64;
    const int ks1 = (sl0 - (row1 >> 1)) & 3;
    const __bf16* gA0 = A + (long)(m0 + row0) * S + kbase + ks0 * 8;
    const __bf16* gA1 = A + (long)(m0 + row1) * S + kbase + ks1 * 8;
    const __bf16* gB0 = B + (long)(n0 + row0) * R + kbase + ks0 * 8;
    __bf16* ldsA0 = As + wave * 512;
    __bf16* ldsA1 = As + 2048 + wave * 512;
    __bf16* ldsB0 = Bs + wave * 512;

    f32x4 acc[4][2];
    #pragma unroll
    for (int i = 0; i < 4; i++)
        #pragma unroll
        for (int j = 0; j < 2; j++) { f32x4 z = {0.f, 0.f, 0.f, 0.f}; acc[i][j] = z; }

    for (int kk = 0; kk < klocal; kk += 32) {
        __syncthreads();
        async_cp16(gA0, ldsA0);
        async_cp16(gA1, ldsA1);
        async_cp16(gB0, ldsB0);
        gA0 += 32; gA1 += 32; gB0 += 32;
        __syncthreads();

        bf16x8 af[4], bg[2];
        #pragma unroll
        for (int i = 0; i < 4; i++)
            af[i] = *(const bf16x8*)(As + swz(wm + i * 16 + l16, quad));
        #pragma unroll
        for (int j = 0; j < 2; j++)
            bg[j] = *(const bf16x8*)(Bs + swz(wn2 + j * 16 + l16, quad));
        #pragma unroll
        for (int i = 0; i < 4; i++)
            #pragma unroll
            for (int j = 0; j < 2; j++)
                acc[i][j] = __builtin_amdgcn_mfma_f32_16x16x32_bf16(bg[j], af[i], acc[i][j], 0, 0, 0);
    }

    __bf16* cb = pbuf + (long)chunk * pstrideE + (long)bz * S * D;
    #pragma unroll
    for (int i = 0; i < 4; i++) {
        const int q = m0 + wm + i * 16 + l16;
        #pragma unroll
        for (int j = 0; j < 2; j++) {
            bf16x4 pk;
            #pragma unroll
            for (int r = 0; r < 4; r++) pk[r] = (__bf16)acc[i][j][r];
            *(bf16x4*)(cb + (long)q * D + n0 + wn2 + j * 16 + quad * 4) = pk;
        }
    }
}

// inv[b*4096+r] = 1 / sum_{slot<lim} side[b][slot][r]; causal lim = 2*(rowtile128+1)
template<bool CAUSAL>
__global__ void reduce_inv(const float* __restrict__ side, float* __restrict__ inv)
{
    const int i = blockIdx.x * 256 + threadIdx.x;     // b*4096 + r
    const int b = i >> 12, r = i & 4095;
    const float* sp = side + (long)b * 64 * 4096 + r;
    const int lim = CAUSAL ? 2 * ((r >> 7) + 1) : 64;
    float s = 0.f;
    for (int t = 0; t < lim; t++) s += sp[(long)t * 4096];
    inv[i] = 1.f / s;
}

// (sum of NP bf16 partials)[*invs] + residual (+ col-bias) -> LayerNorm(D=256)
template<int NP>
__launch_bounds__(256)
__global__ void ln_res(const __bf16* __restrict__ p, long pstr,
                       const float* __restrict__ resid, const float* __restrict__ invs,
                       const float* __restrict__ bias,
                       const float* __restrict__ gamma, const float* __restrict__ beta,
                       float* __restrict__ outf, __bf16* __restrict__ outb)
{
    const int row  = blockIdx.x * 4 + (threadIdx.x >> 6);
    const int lane = threadIdx.x & 63;
    const long vi = (long)row * 64 + lane;
    float p0 = 0.f, p1 = 0.f, p2 = 0.f, p3 = 0.f;
    #pragma unroll
    for (int i = 0; i < NP; i++) {
        bf16x4 vp = ((const bf16x4*)(p + (long)i * pstr))[vi];
        p0 += (float)vp[0]; p1 += (float)vp[1]; p2 += (float)vp[2]; p3 += (float)vp[3];
    }
    if (invs) { const float iv = invs[row]; p0 *= iv; p1 *= iv; p2 *= iv; p3 *= iv; }
    float4 vr = ((const float4*)resid)[vi];
    float x0 = vr.x + p0, x1 = vr.y + p1, x2 = vr.z + p2, x3 = vr.w + p3;
    if (bias) {
        float4 vb = ((const float4*)bias)[lane];
        x0 += vb.x; x1 += vb.y; x2 += vb.z; x3 += vb.w;
    }
    float s = x0 + x1 + x2 + x3;
    #pragma unroll
    for (int off = 32; off; off >>= 1) s += __shfl_xor(s, off);
    const float mu = s * (1.f / 256.f);
    float d0 = x0 - mu, d1 = x1 - mu, d2 = x2 - mu, d3 = x3 - mu;
    float s2 = d0 * d0 + d1 * d1 + d2 * d2 + d3 * d3;
    #pragma unroll
    for (int off = 32; off; off >>= 1) s2 += __shfl_xor(s2, off);
    const float rs = rsqrtf(s2 * (1.f / 256.f) + 1e-3f);
    const float4 g  = ((const float4*)gamma)[lane];
    const float4 be = ((const float4*)beta)[lane];
    float o0 = d0 * rs * g.x + be.x, o1 = d1 * rs * g.y + be.y;
    float o2 = d2 * rs * g.z + be.z, o3 = d3 * rs * g.w + be.w;
    float4 o; o.x = o0; o.y = o1; o.z = o2; o.w = o3;
    ((float4*)outf)[vi] = o;
    if (outb) {
        bf16x4 ob; ob[0] = (__bf16)o0; ob[1] = (__bf16)o1; ob[2] = (__bf16)o2; ob[3] = (__bf16)o3;
        ((bf16x4*)outb)[vi] = ob;
    }
}

__device__ __forceinline__ void tp(const float* __restrict__ src, __bf16* __restrict__ dst,
                                   int rows, int cols, int rowsP, int i)
{
    const int c = i / rowsP, r = i - c * rowsP;
    const float v = (r < rows && c < cols) ? src[r * cols + c] : 0.f;
    dst[i] = (__bf16)v;
}

// one kernel for all prep: fp32->bf16 converts + weight transposes + bias pad
__global__ void prep_all(const float4* __restrict__ inA, const float4* __restrict__ inC,
                         bf16x4* __restrict__ outA, bf16x4* __restrict__ outC,
                         const float* __restrict__ sWq, const float* __restrict__ sWk,
                         const float* __restrict__ sWv,
                         const float* __restrict__ cWq, const float* __restrict__ cWk,
                         const float* __restrict__ cWv,
                         const float* __restrict__ W1, const float* __restrict__ W2,
                         __bf16* __restrict__ wqk_s, __bf16* __restrict__ wv_s,
                         __bf16* __restrict__ wq_c, __bf16* __restrict__ wk_c,
                         __bf16* __restrict__ wv_c,
                         __bf16* __restrict__ W1t, __bf16* __restrict__ W2t,
                         const float* __restrict__ b1, float* __restrict__ b1p)
{
    const int bx = blockIdx.x, tid = threadIdx.x;
    if (bx < 8192) {
        const bool a = bx < 4096;
        const long j = (long)(a ? bx : bx - 4096) * 256 + tid;
        float4 v = (a ? inA : inC)[j];
        bf16x4 o; o[0] = (__bf16)v.x; o[1] = (__bf16)v.y; o[2] = (__bf16)v.z; o[3] = (__bf16)v.w;
        (a ? outA : outC)[j] = o;
    }
    else if (bx < 8448)  tp(sWq, wqk_s,          256, 256, 256, (bx - 8192)  * 256 + tid);
    else if (bx < 8704)  tp(sWk, wqk_s + 65536,  256, 256, 256, (bx - 8448)  * 256 + tid);
    else if (bx < 8960)  tp(sWv, wv_s,           256, 256, 256, (bx - 8704)  * 256 + tid);
    else if (bx < 9216)  tp(cWq, wq_c,           256, 256, 256, (bx - 8960)  * 256 + tid);
    else if (bx < 9472)  tp(cWk, wk_c,           256, 256, 256, (bx - 9216)  * 256 + tid);
    else if (bx < 9728)  tp(cWv, wv_c,           256, 256, 256, (bx - 9472)  * 256 + tid);
    else if (bx < 10240) tp(W1,  W1t,            256, 400, 256, (bx - 9728)  * 256 + tid);
    else if (bx < 10752) tp(W2,  W2t,            400, 256, 512, (bx - 10240) * 256 + tid);
    else { const int i = (bx - 10752) * 256 + tid; if (i < 512) b1p[i] = (i < 400) ? b1[i] : 0.f; }
}

extern "C" void kernel_launch(void* const* d_in, const int* in_sizes, int n_in,
                              void* d_out, int out_size, void* d_ws, size_t ws_size,
                              hipStream_t stream)
{
    constexpr int B = 4, S = 4096, D = 256, H = 400, Hp = 512;
    constexpr int R = B * S;
    constexpr float SCALE = 1.f / 64.f;   // 1/sqrt(4096)

    const float* inputs = (const float*)d_in[0];
    const float* ctx    = (const float*)d_in[1];
    const float* sa_Wk  = (const float*)d_in[2];
    const float* sa_Wv  = (const float*)d_in[3];
    const float* sa_Wq  = (const float*)d_in[4];
    const float* ca_Wk  = (const float*)d_in[5];
    const float* ca_Wv  = (const float*)d_in[6];
    const float* ca_Wq  = (const float*)d_in[7];
    const float* W1     = (const float*)d_in[8];
    const float* b1     = (const float*)d_in[9];
    const float* W2     = (const float*)d_in[10];
    const float* b2     = (const float*)d_in[11];
    const float* gamma  = (const float*)d_in[12];
    const float* beta   = (const float*)d_in[13];
    float* out = (float*)d_out;

    char* ws = (char*)d_ws;
    size_t off = 0;
    auto alloc = [&](size_t bytes) -> char* {
        char* p = ws + off; off += (bytes + 255) & ~size_t(255); return p;
    };
    __bf16* bfA  = (__bf16*)alloc((size_t)R * D * 2);     // bf16(inputs) -> xbf
    __bf16* bfC  = (__bf16*)alloc((size_t)R * D * 2);     // bf16(context) -> ybf
    __bf16* Qb   = (__bf16*)alloc((size_t)R * D * 2);
    __bf16* Kb   = (__bf16*)alloc((size_t)R * D * 2);
    __bf16* Vt   = (__bf16*)alloc((size_t)D * R * 2);     // V^T: [256][B*S]
    __bf16* h    = (__bf16*)alloc((size_t)R * Hp * 2);    // FFN hidden
    float*  x    = (float*)alloc((size_t)R * D * 4);
    float*  y    = (float*)alloc((size_t)R * D * 4);
    float*  side = (float*)alloc((size_t)B * 64 * S * 4); // row-sums per 64-col slot
    float*  invb = (float*)alloc((size_t)B * S * 4);      // 1/rowsum
    __bf16* wqk_s = (__bf16*)alloc((size_t)2 * D * D * 2); // [Wq^T | Wk^T] (self)
    __bf16* wv_s  = (__bf16*)alloc((size_t)D * D * 2);
    __bf16* wq_c  = (__bf16*)alloc((size_t)D * D * 2);
    __bf16* wk_c  = (__bf16*)alloc((size_t)D * D * 2);
    __bf16* wv_c  = (__bf16*)alloc((size_t)D * D * 2);
    __bf16* W1t  = (__bf16*)alloc((size_t)Hp * D * 2);
    __bf16* W2t  = (__bf16*)alloc((size_t)D * Hp * 2);
    float*  b1p  = (float*)alloc((size_t)Hp * 4);

    const size_t PBb = (size_t)R * D * 2;            // one bf16 partial buffer (8MB)
    const size_t SCB = (size_t)B * S * S * 2;        // batched scores (128MB)
    size_t rem = ws_size > off ? ws_size - off : 0;
    int NS;
    if      (rem >= 4 * PBb + SCB) NS = 4;
    else if (rem >= 2 * PBb + SCB) NS = 2;
    else if (rem >= 1 * PBb + SCB) NS = 1;
    else return;                                     // workspace too small
    __bf16* pbuf = (__bf16*)alloc((size_t)NS * PBb);
    __bf16* SC   = (__bf16*)(ws + off);
    const long PBe = (long)R * D;                    // partial stride (elements)

    __bf16* xbf = bfA;
    __bf16* ybf = bfC;

    const dim3 blk(256);
    const int pvGrid = 4 * 32 * NS * B;              // flat XCD-grouped grid
    const dim3 gSc(64, 64, B);

    auto launch_ln = [&](int np, const float* res, const float* invs, const float* bias,
                         float* of, __bf16* ob) {
        if (np == 4)      ln_res<4><<<R / 4, blk, 0, stream>>>(pbuf, PBe, res, invs, bias, gamma, beta, of, ob);
        else if (np == 2) ln_res<2><<<R / 4, blk, 0, stream>>>(pbuf, PBe, res, invs, bias, gamma, beta, of, ob);
        else              ln_res<1><<<R / 4, blk, 0, stream>>>(pbuf, PBe, res, invs, bias, gamma, beta, of, ob);
    };

    // --- prep (single consolidated dispatch) ---
    prep_all<<<10754, blk, 0, stream>>>((const float4*)inputs, (const float4*)ctx,
        (bf16x4*)bfA, (bf16x4*)bfC, sa_Wq, sa_Wk, sa_Wv, ca_Wq, ca_Wk, ca_Wv, W1, W2,
        wqk_s, wv_s, wq_c, wk_c, wv_c, W1t, W2t, b1, b1p);

    // --- self-attention (causal) ---
    gemm_nt<4><<<dim3(4, 128, 1), blk, 0, stream>>>(bfA, wqk_s, nullptr,
        Qb, Kb, nullptr, 2 * D, D, D, 0, 0, 0, 4, D, 0);
    gemm_nt<1><<<dim3(128, 2, 1), blk, 0, stream>>>(wv_s, bfA, nullptr,
        Vt, nullptr, nullptr, R, D, D, 0, 0, 0, 128, D, 0);
    scores_nt<true><<<gSc, blk, 0, stream>>>(Qb, Kb, SC, side, SCALE);
    reduce_inv<true><<<R / 256, blk, 0, stream>>>(side, invb);
    pv_nt<2><<<pvGrid, blk, 0, stream>>>(SC, Vt, pbuf, NS, PBe);
    launch_ln(NS, inputs, invb, nullptr, x, xbf);

    // --- cross-attention (full): Q from x, K/V^T from context ---
    gemm_nt<1><<<dim3(2, 128, 1), blk, 0, stream>>>(xbf, wq_c, nullptr,
        Qb, nullptr, nullptr, D, D, D, 0, 0, 0, 2, D, 0);
    gemm_nt<1><<<dim3(2, 128, 1), blk, 0, stream>>>(bfC, wk_c, nullptr,
        Kb, nullptr, nullptr, D, D, D, 0, 0, 0, 2, D, 0);
    gemm_nt<1><<<dim3(128, 2, 1), blk, 0, stream>>>(wv_c, bfC, nullptr,
        Vt, nullptr, nullptr, R, D, D, 0, 0, 0, 128, D, 0);
    scores_nt<false><<<gSc, blk, 0, stream>>>(Qb, Kb, SC, side, SCALE);
    reduce_inv<false><<<R / 256, blk, 0, stream>>>(side, invb);
    pv_nt<0><<<pvGrid, blk, 0, stream>>>(SC, Vt, pbuf, NS, PBe);
    launch_ln(NS, x, invb, nullptr, y, ybf);

    // --- FFN ---
    gemm_nt<2><<<dim3(4, 128, 1), blk, 0, stream>>>(ybf, W1t, b1p,
        h, nullptr, nullptr, Hp, D, D, 0, 0, 0, 4, D, 0);
    gemm_nt<3><<<dim3(2 * NS, 128, 1), blk, 0, stream>>>(h, W2t, nullptr,
        pbuf, nullptr, nullptr, D, Hp, Hp, 0, 0, 0, 2, Hp / NS, (long)PBb);
    launch_ln(NS, y, nullptr, b2, out, nullptr);   // b2 folded into pre-LN sum
}